// Round 5
// baseline (413.823 us; speedup 1.0000x reference)
//
#include <hip/hip_runtime.h>

#define SEQ_T   2048
#define BATCH_N 4096
#define LOG2E   1.4426950408889634f
#define PF      8

typedef unsigned int v2u __attribute__((ext_vector_type(2)));

// DPP mov: quad_perm = 0x00..0xFF, ROW_MIRROR = 0x140, ROW_HALF_MIRROR = 0x141
#define DPPF(v, ctrl) __int_as_float(__builtin_amdgcn_mov_dpp(__float_as_int(v), (ctrl), 0xF, 0xF, true))

// Layout: 32 lanes per chain, split by layer across the 32-lane halves.
//   lane = 32*layer + 16*cpos + (4u + r)   (cpos = chain-in-wave, 2 chains/wave)
// Both halves run IDENTICAL scalar cell code; only per-lane weight registers
// differ. Layer-1 runs 1 step behind; h0 crosses the 32-boundary via ONE
// v_permlane32_swap per step (VALU). Gate gather: quad_perm DPP. h distribute:
// mirror DPPs (row-local, works independently in each 16-lane row).
// 4096 chains * 32 lanes = 131072 threads = 2048 waves = 2 waves/SIMD.
__global__ __launch_bounds__(256, 2) void lstm2_fused(
    const float* __restrict__ x,
    const float* __restrict__ Wih0, const float* __restrict__ Whh0,
    const float* __restrict__ bih0, const float* __restrict__ bhh0,
    const float* __restrict__ Wih1, const float* __restrict__ Whh1,
    const float* __restrict__ bih1, const float* __restrict__ bhh1,
    float* __restrict__ out)
{
    const int tid   = blockIdx.x * blockDim.x + threadIdx.x;
    const int lane  = threadIdx.x & 63;
    const int wid   = tid >> 6;            // global wave id
    const int cpos  = (lane >> 4) & 1;     // chain-in-wave
    const int chain = wid * 2 + cpos;
    const int g16   = lane & 15;
    const int u     = g16 >> 2;            // hidden unit (quad)
    const int r     = g16 & 3;             // role 0=i 1=f 2=g 3=o
    const int row   = r * 4 + u;           // PyTorch gate-row index
    const bool islo = (lane < 32);         // layer 0 half

    // Per-lane weights: lo lanes = layer0 (input dot in natural order, for x),
    // hi lanes = layer1 (input dot in u-relative order, for h0 mirrors).
    // Fold -log2e (sigmoid) / -2log2e (tanh row) into weights & bias.
    const float srow = (r == 2) ? (-2.0f * LOG2E) : (-LOG2E);
    float win[4], whh[4];
#pragma unroll
    for (int d = 0; d < 4; ++d) {
        win[d] = (islo ? Wih0[row * 4 + d] : Wih1[row * 4 + (u ^ d)]) * srow;
        whh[d] = (islo ? Whh0[row * 4 + (u ^ d)] : Whh1[row * 4 + (u ^ d)]) * srow;
    }
    const float bb = (islo ? (bih0[row] + bhh0[row]) : (bih1[row] + bhh1[row])) * srow;
    const float ka = (r == 2) ?  2.0f : 1.0f;   // act = ka*sigma + kb
    const float kb = (r == 2) ? -1.0f : 0.0f;

    // One-time semantics probe for permlane32_swap output selection:
    // the correct output holds (lane&31)'s lo-half value on every lane.
    v2u pp = __builtin_amdgcn_permlane32_swap((unsigned)lane, (unsigned)lane,
                                              false, false);
    const bool use1 = (pp[1] == (unsigned)(lane & 31));

    const float4* __restrict__ x4 = (const float4*)x;   // [T][B] as float4
    float4* __restrict__ out4 = (float4*)out;

    float cc = 0.f;
    float hh = 0.f, hha = 0.f, hhb = 0.f, hhc = 0.f;  // u-relative h state

    auto step = [&](const float4 xv, int kout, bool do_store) {
        // ---- transfer lo-half hh (h0 of prev step) to hi lanes ----
        unsigned hb = __float_as_uint(hh);
        v2u pr = __builtin_amdgcn_permlane32_swap(hb, hb, false, false);
        float X  = __uint_as_float(use1 ? pr[1] : pr[0]);
        float Xa = DPPF(X,  0x141);     // h0_{u^1}
        float Xc = DPPF(X,  0x140);     // h0_{u^3}
        float Xb = DPPF(Xa, 0x140);     // h0_{u^2}
        // input operands: lo = x components (natural), hi = h0 mirrors (u-rel)
        float i0 = islo ? xv.x : X;
        float i1 = islo ? xv.y : Xa;
        float i2 = islo ? xv.z : Xb;
        float i3 = islo ? xv.w : Xc;
        // pre-activation: bias + input dot + recurrent dot (freshest last)
        float p = fmaf(win[0], i0, fmaf(win[1], i1,
                  fmaf(win[2], i2, fmaf(win[3], i3, bb))));
        p = fmaf(whh[1], hha, fmaf(whh[3], hhc,
            fmaf(whh[0], hh,  fmaf(whh[2], hhb, p))));
        // activation (sigma; tanh row via ka,kb)
        float s = __builtin_amdgcn_rcpf(1.0f + __builtin_amdgcn_exp2f(p));
        float a = fmaf(ka, s, kb);
        // gate gather (intra-quad broadcast)
        float iv = DPPF(a, 0x00);
        float fv = DPPF(a, 0x55);
        float gv = DPPF(a, 0xAA);
        float ov = DPPF(a, 0xFF);
        // cell update + output
        cc = fmaf(fv, cc, iv * gv);
        float ec = __builtin_amdgcn_exp2f(cc * (-2.0f * LOG2E));
        float th = fmaf(2.0f, __builtin_amdgcn_rcpf(1.0f + ec), -1.0f);
        hh  = ov * th;
        hha = DPPF(hh,  0x141);
        hhc = DPPF(hh,  0x140);
        hhb = DPPF(hha, 0x140);
        // hi half just produced h1(kout); lane g16==0 has natural order
        if (do_store && !islo && g16 == 0) {
            out4[kout * BATCH_N + chain] = make_float4(hh, hha, hhb, hhc);
        }
    };

    // ---- peel step 0: layer0 consumes x(0); hi half computes garbage ----
    step(x4[chain], 0, false);
    // zero the hi-half (layer1) state corrupted by the peel
    cc  = islo ? cc  : 0.f;
    hh  = islo ? hh  : 0.f;
    hha = islo ? hha : 0.f;
    hhb = islo ? hhb : 0.f;
    hhc = islo ? hhc : 0.f;

    // x prefetch ring: x(1..PF)
    float4 xbuf[PF];
#pragma unroll
    for (int i = 0; i < PF; ++i) xbuf[i] = x4[(1 + i) * BATCH_N + chain];

    // main loop: iteration k runs L0 step k (lo) and L1 step k-1 (hi)
    for (int kk = 1; kk <= SEQ_T; kk += PF) {
#pragma unroll
        for (int q = 0; q < PF; ++q) {
            const int k = kk + q;
            const float4 xv = xbuf[q];
            int tp = k + PF; tp = (tp > SEQ_T - 1) ? (SEQ_T - 1) : tp;
            xbuf[q] = x4[tp * BATCH_N + chain];
            step(xv, k - 1, true);
        }
    }
}

extern "C" void kernel_launch(void* const* d_in, const int* in_sizes, int n_in,
                              void* d_out, int out_size, void* d_ws, size_t ws_size,
                              hipStream_t stream) {
    const float* x    = (const float*)d_in[0];
    const float* Wih0 = (const float*)d_in[1];
    const float* Whh0 = (const float*)d_in[2];
    const float* bih0 = (const float*)d_in[3];
    const float* bhh0 = (const float*)d_in[4];
    const float* Wih1 = (const float*)d_in[5];
    const float* Whh1 = (const float*)d_in[6];
    const float* bih1 = (const float*)d_in[7];
    const float* bhh1 = (const float*)d_in[8];
    float* out = (float*)d_out;

    // 4096 chains * 32 lanes = 131072 threads = 2048 waves = 2 waves/SIMD
    dim3 grid(512), block(256);
    hipLaunchKernelGGL(lstm2_fused, grid, block, 0, stream,
                       x, Wih0, Whh0, bih0, bhh0, Wih1, Whh1, bih1, bhh1, out);
}

// Round 6
// 321.177 us; speedup vs baseline: 1.2885x; 1.2885x over previous
//
#include <hip/hip_runtime.h>

#define SEQ_T   2048
#define BATCH_N 4096
#define LOG2E   1.4426950408889634f
#define PF      8

// DPP mov: quad_perm = 0x00..0xFF, ROW_MIRROR = 0x140, ROW_HALF_MIRROR = 0x141
#define DPPF(v, ctrl) __int_as_float(__builtin_amdgcn_mov_dpp(__float_as_int(v), (ctrl), 0xF, 0xF, true))
#define RHM 0x141   // quad u -> u^1 (intra-quad scramble irrelevant: h is quad-uniform)
#define MIR 0x140   // quad u -> u^3

// 16 lanes per chain, UNIT-MAJOR: lane-in-16 = 4*u + r (u=unit=quad, r=role).
// PyTorch row = r*4+u. Gate gather: quad_perm DPP. h distribute: mirror DPPs.
// Two scalar, explicitly separate dependency chains per iteration:
//   L0 advances step k, L1 advances step k-1 (consumes h0(k-1) = pre-update h0).
// All per-step addressing is 32-bit byte offsets off base pointers.
__global__ __launch_bounds__(256, 1) void lstm2_fused(
    const float* __restrict__ x,
    const float* __restrict__ Wih0, const float* __restrict__ Whh0,
    const float* __restrict__ bih0, const float* __restrict__ bhh0,
    const float* __restrict__ Wih1, const float* __restrict__ Whh1,
    const float* __restrict__ bih1, const float* __restrict__ bhh1,
    float* __restrict__ out)
{
    const int tid   = blockIdx.x * blockDim.x + threadIdx.x;
    const int g16   = tid & 15;
    const int u     = g16 >> 2;          // hidden unit (quad)
    const int r     = g16 & 3;           // role 0=i 1=f 2=g 3=o
    const int chain = tid >> 4;          // batch element
    const int row   = r * 4 + u;         // PyTorch gate-row index

    // Fold -log2e (sigmoid) / -2log2e (tanh row) into weights & bias.
    const float srow = (r == 2) ? (-2.0f * LOG2E) : (-LOG2E);
    float wih0[4], whh0[4], wih1[4], whh1[4];
#pragma unroll
    for (int d = 0; d < 4; ++d) {
        wih0[d] = Wih0[row * 4 + d]       * srow;  // natural order (x input)
        whh0[d] = Whh0[row * 4 + (u ^ d)] * srow;  // u-relative order
        wih1[d] = Wih1[row * 4 + (u ^ d)] * srow;
        whh1[d] = Whh1[row * 4 + (u ^ d)] * srow;
    }
    const float b0 = (bih0[row] + bhh0[row]) * srow;
    const float b1 = (bih1[row] + bhh1[row]) * srow;
    const float ka = (r == 2) ?  2.0f : 1.0f;   // act = ka*sigma + kb
    const float kb = (r == 2) ? -1.0f : 0.0f;

    const char* __restrict__ xb = (const char*)x;
    char* __restrict__ ob = (char*)out;
    const unsigned xhome = (unsigned)chain * 16u;            // &x[0][chain][0]
    const unsigned XCL   = xhome + 2047u * 65536u;           // last-step clamp
    unsigned ooff = (unsigned)(chain * 16 + u * 4);          // out row 0, my unit

    // ---- peel: L0 step 0 (h0(-1)=0, c0(-1)=0) ----
    const float4 xv0 = *(const float4*)(xb + xhome);
    float p = fmaf(wih0[0], xv0.x, fmaf(wih0[1], xv0.y,
              fmaf(wih0[2], xv0.z, fmaf(wih0[3], xv0.w, b0))));
    float s = __builtin_amdgcn_rcpf(1.0f + __builtin_amdgcn_exp2f(p));
    float a = fmaf(ka, s, kb);
    float iv = DPPF(a, 0x00);
    float gv = DPPF(a, 0xAA);
    float ov = DPPF(a, 0xFF);
    float cc0 = iv * gv;                       // f*c(-1) term drops
    float ec = __builtin_amdgcn_exp2f(cc0 * (-2.0f * LOG2E));
    float th = fmaf(2.0f, __builtin_amdgcn_rcpf(1.0f + ec), -1.0f);
    float h0 = ov * th;
    float h1 = 0.f, cc1 = 0.f;

    // ---- x prefetch ring: steps 1..PF ----
    float4 xbuf[PF];
    unsigned xoffpf = xhome + 65536u;
#pragma unroll
    for (int i = 0; i < PF; ++i) {
        xbuf[i] = *(const float4*)(xb + xoffpf);
        xoffpf += 65536u;
    }
    // xoffpf now points at step PF+1

    // ---- main loop: iteration k = L0 step k, L1 step k-1 ----
    for (int kk = 1; kk <= SEQ_T; kk += PF) {
#pragma unroll
        for (int q = 0; q < PF; ++q) {
            const float4 xv = xbuf[q];
            unsigned off = (xoffpf < XCL) ? xoffpf : XCL;
            xbuf[q] = *(const float4*)(xb + off);
            xoffpf += 65536u;

            // L1 recurrent dot (old h1 = h1(k-2))
            float h1a = DPPF(h1, RHM);
            float h1c = DPPF(h1, MIR);
            float h1b = DPPF(h1a, MIR);
            float acc1 = fmaf(whh1[0], h1,
                         fmaf(whh1[1], h1a,
                         fmaf(whh1[2], h1b,
                         fmaf(whh1[3], h1c, b1))));
            // L0 input dot (independent filler)
            float acc0 = fmaf(wih0[0], xv.x,
                         fmaf(wih0[1], xv.y,
                         fmaf(wih0[2], xv.z,
                         fmaf(wih0[3], xv.w, b0))));
            // h0(k-1) mirrors feed BOTH layers
            float h0a = DPPF(h0, RHM);
            float h0c = DPPF(h0, MIR);
            float h0b = DPPF(h0a, MIR);
            // L0 recurrent dot
            acc0 = fmaf(whh0[0], h0,
                   fmaf(whh0[1], h0a,
                   fmaf(whh0[2], h0b,
                   fmaf(whh0[3], h0c, acc0))));
            // L1 input dot
            acc1 = fmaf(wih1[0], h0,
                   fmaf(wih1[1], h0a,
                   fmaf(wih1[2], h0b,
                   fmaf(wih1[3], h0c, acc1))));
            // activations — trans ops paired so the two chains pipeline
            float e0 = __builtin_amdgcn_exp2f(acc0);
            float e1 = __builtin_amdgcn_exp2f(acc1);
            float s0 = __builtin_amdgcn_rcpf(1.0f + e0);
            float s1 = __builtin_amdgcn_rcpf(1.0f + e1);
            float a0 = fmaf(ka, s0, kb);
            float a1 = fmaf(ka, s1, kb);
            // gate gathers (intra-quad broadcasts)
            float iv0 = DPPF(a0, 0x00), fv0 = DPPF(a0, 0x55);
            float gv0 = DPPF(a0, 0xAA), ov0 = DPPF(a0, 0xFF);
            float iv1 = DPPF(a1, 0x00), fv1 = DPPF(a1, 0x55);
            float gv1 = DPPF(a1, 0xAA), ov1 = DPPF(a1, 0xFF);
            // cell updates
            cc0 = fmaf(fv0, cc0, iv0 * gv0);
            cc1 = fmaf(fv1, cc1, iv1 * gv1);
            float z0 = __builtin_amdgcn_exp2f(cc0 * (-2.0f * LOG2E));
            float z1 = __builtin_amdgcn_exp2f(cc1 * (-2.0f * LOG2E));
            float t0 = fmaf(2.0f, __builtin_amdgcn_rcpf(1.0f + z0), -1.0f);
            float t1 = fmaf(2.0f, __builtin_amdgcn_rcpf(1.0f + z1), -1.0f);
            h0 = ov0 * t0;     // h0(k)
            h1 = ov1 * t1;     // h1(k-1)

            // r==0 lanes each store their own unit's h1 -> 16B/chain contiguous
            if (r == 0) {
                *(float*)(ob + ooff) = h1;
            }
            ooff += 65536u;
        }
    }
}

extern "C" void kernel_launch(void* const* d_in, const int* in_sizes, int n_in,
                              void* d_out, int out_size, void* d_ws, size_t ws_size,
                              hipStream_t stream) {
    const float* x    = (const float*)d_in[0];
    const float* Wih0 = (const float*)d_in[1];
    const float* Whh0 = (const float*)d_in[2];
    const float* bih0 = (const float*)d_in[3];
    const float* bhh0 = (const float*)d_in[4];
    const float* Wih1 = (const float*)d_in[5];
    const float* Whh1 = (const float*)d_in[6];
    const float* bih1 = (const float*)d_in[7];
    const float* bhh1 = (const float*)d_in[8];
    float* out = (float*)d_out;

    // 4096 chains * 16 lanes = 1024 waves = 1 wave per SIMD machine-wide
    dim3 grid(256), block(256);
    hipLaunchKernelGGL(lstm2_fused, grid, block, 0, stream,
                       x, Wih0, Whh0, bih0, bhh0, Wih1, Whh1, bih1, bhh1, out);
}

// Round 7
// 284.474 us; speedup vs baseline: 1.4547x; 1.1290x over previous
//
#include <hip/hip_runtime.h>

#define SEQ_T   2048
#define BATCH_N 4096
#define LOG2E   1.4426950408889634f
#define K_SEG   8
#define NSEG    (SEQ_T / K_SEG)   // 256 segments

// DPP mov: quad_perm = 0x00..0xFF, ROW_MIRROR = 0x140, ROW_HALF_MIRROR = 0x141
#define DPPF(v, ctrl) __int_as_float(__builtin_amdgcn_mov_dpp(__float_as_int(v), (ctrl), 0xF, 0xF, true))
#define RHM 0x141   // quad u -> u^1 (h is quad-uniform, intra-quad scramble ok)
#define MIR 0x140   // quad u -> u^3

// Layer-split wave specialization:
//   waves 0,1 of each 256-thread block = "A" (layer 0, chains 0-7 local)
//   waves 2,3                          = "B" (layer 1, same chains, 1 segment behind)
// 16 lanes per chain, UNIT-MAJOR lane-in-16 = 4*u + r (PyTorch row = r*4+u).
// h0 handoff: LDS ring [16 slots][8 chains][4 units]; __syncthreads every 8
// steps; segment parity gives disjoint ring halves (A writes s*8..s*8+7 & 15,
// B reads the previous segment's half). 2048 waves = 2 waves/SIMD.
__global__ __launch_bounds__(256, 2) void lstm2_split(
    const float* __restrict__ x,
    const float* __restrict__ Wih0, const float* __restrict__ Whh0,
    const float* __restrict__ bih0, const float* __restrict__ bhh0,
    const float* __restrict__ Wih1, const float* __restrict__ Whh1,
    const float* __restrict__ bih1, const float* __restrict__ bhh1,
    float* __restrict__ out)
{
    __shared__ float ring[16][8][4];   // [slot][local chain][unit]

    const int wv    = threadIdx.x >> 6;     // wave in block: 0..3
    const int lane  = threadIdx.x & 63;
    const int cpos  = lane >> 4;            // chain-in-wave 0..3
    const int g16   = lane & 15;
    const int u     = g16 >> 2;             // hidden unit (quad)
    const int r     = g16 & 3;              // role 0=i 1=f 2=g 3=o
    const int row   = r * 4 + u;            // PyTorch gate-row
    const bool isA  = (wv < 2);             // layer-0 waves
    const int lch   = (wv & 1) * 4 + cpos;  // local chain 0..7
    const int chain = blockIdx.x * 8 + lch;

    // Per-lane weights. A: input dot in natural order (x components).
    //                   B: input dot in u-relative order (h0 mirrors).
    // Fold -log2e (sigmoid) / -2log2e (tanh row) into weights & bias.
    const float srow = (r == 2) ? (-2.0f * LOG2E) : (-LOG2E);
    float win[4], whh[4];
    float bb;
    if (isA) {
#pragma unroll
        for (int d = 0; d < 4; ++d) {
            win[d] = Wih0[row * 4 + d]       * srow;
            whh[d] = Whh0[row * 4 + (u ^ d)] * srow;
        }
        bb = (bih0[row] + bhh0[row]) * srow;
    } else {
#pragma unroll
        for (int d = 0; d < 4; ++d) {
            win[d] = Wih1[row * 4 + (u ^ d)] * srow;
            whh[d] = Whh1[row * 4 + (u ^ d)] * srow;
        }
        bb = (bih1[row] + bhh1[row]) * srow;
    }
    // Gate activation: a = ka*sigma + kb. For the g-row, additionally fold
    // the cell-tanh argument scale (-2log2e) so cell state is tracked
    // pre-scaled: cs = f*cs + i*(g * -2log2e);  z = exp2(cs) directly.
    const float csc = -2.0f * LOG2E;
    float ka = (r == 2) ? 2.0f * csc : 1.0f;
    float kb = (r == 2) ? -1.0f * csc : 0.0f;

    const char* __restrict__ xb = (const char*)x;
    char* __restrict__ ob = (char*)out;

    float h = 0.f, ha = 0.f, hb2 = 0.f, hc = 0.f;  // my layer's h, u-relative
    float cs = 0.f;                                 // pre-scaled cell state

    if (isA) {
        // ---------------- layer-0 wave ----------------
        const unsigned xhome = (unsigned)chain * 16u;
        float4 xreg[K_SEG];
        unsigned xoff = xhome;
#pragma unroll
        for (int i = 0; i < K_SEG; ++i) {           // prologue: x(0..7)
            xreg[i] = *(const float4*)(xb + xoff);
            xoff += 65536u;
        }
        for (int seg = 0; seg <= NSEG; ++seg) {
            __syncthreads();
            if (seg < NSEG) {
                const int slotbase = (seg * K_SEG) & 15;
                const bool pf = (seg + 1 < NSEG);
#pragma unroll
                for (int i = 0; i < K_SEG; ++i) {
                    const float4 xv = xreg[i];
                    if (pf) {
                        xreg[i] = *(const float4*)(xb + xoff);
                        xoff += 65536u;
                    }
                    float acc = fmaf(win[0], xv.x, fmaf(win[1], xv.y,
                                fmaf(win[2], xv.z, fmaf(win[3], xv.w, bb))));
                    acc = fmaf(whh[0], h, fmaf(whh[1], ha,
                          fmaf(whh[2], hb2, fmaf(whh[3], hc, acc))));
                    float e = __builtin_amdgcn_exp2f(acc);
                    float s = __builtin_amdgcn_rcpf(1.0f + e);
                    float a = fmaf(ka, s, kb);
                    float iv = DPPF(a, 0x00), fv = DPPF(a, 0x55);
                    float gv = DPPF(a, 0xAA), ov = DPPF(a, 0xFF);
                    cs = fmaf(fv, cs, iv * gv);
                    float z = __builtin_amdgcn_exp2f(cs);
                    float t2 = fmaf(2.0f, __builtin_amdgcn_rcpf(1.0f + z), -1.0f);
                    h  = ov * t2;
                    ha = DPPF(h, RHM);
                    hc = DPPF(h, MIR);
                    hb2 = DPPF(ha, MIR);
                    if (r == 0) ring[slotbase + i][lch][u] = h;
                }
            }
        }
    } else {
        // ---------------- layer-1 wave ----------------
        unsigned ooff = (unsigned)(chain * 16 + u * 4);   // out[0][chain][u]
        for (int seg = 0; seg <= NSEG; ++seg) {
            __syncthreads();
            if (seg > 0) {
                const int slotbase = ((seg - 1) * K_SEG) & 15;
                float hreg[K_SEG];
#pragma unroll
                for (int i = 0; i < K_SEG; ++i)
                    hreg[i] = ring[slotbase + i][lch][u];
#pragma unroll
                for (int i = 0; i < K_SEG; ++i) {
                    const float X = hreg[i];
                    float Xa = DPPF(X, RHM);
                    float Xc = DPPF(X, MIR);
                    float Xb = DPPF(Xa, MIR);
                    float acc = fmaf(win[0], X, fmaf(win[1], Xa,
                                fmaf(win[2], Xb, fmaf(win[3], Xc, bb))));
                    acc = fmaf(whh[0], h, fmaf(whh[1], ha,
                          fmaf(whh[2], hb2, fmaf(whh[3], hc, acc))));
                    float e = __builtin_amdgcn_exp2f(acc);
                    float s = __builtin_amdgcn_rcpf(1.0f + e);
                    float a = fmaf(ka, s, kb);
                    float iv = DPPF(a, 0x00), fv = DPPF(a, 0x55);
                    float gv = DPPF(a, 0xAA), ov = DPPF(a, 0xFF);
                    cs = fmaf(fv, cs, iv * gv);
                    float z = __builtin_amdgcn_exp2f(cs);
                    float t2 = fmaf(2.0f, __builtin_amdgcn_rcpf(1.0f + z), -1.0f);
                    h  = ov * t2;
                    ha = DPPF(h, RHM);
                    hc = DPPF(h, MIR);
                    hb2 = DPPF(ha, MIR);
                    if (r == 0) *(float*)(ob + ooff) = h;   // h1 of my unit
                    ooff += 65536u;
                }
            }
        }
    }
}

extern "C" void kernel_launch(void* const* d_in, const int* in_sizes, int n_in,
                              void* d_out, int out_size, void* d_ws, size_t ws_size,
                              hipStream_t stream) {
    const float* x    = (const float*)d_in[0];
    const float* Wih0 = (const float*)d_in[1];
    const float* Whh0 = (const float*)d_in[2];
    const float* bih0 = (const float*)d_in[3];
    const float* bhh0 = (const float*)d_in[4];
    const float* Wih1 = (const float*)d_in[5];
    const float* Whh1 = (const float*)d_in[6];
    const float* bih1 = (const float*)d_in[7];
    const float* bhh1 = (const float*)d_in[8];
    float* out = (float*)d_out;

    // 512 blocks * 4 waves = 2048 waves = 2 waves/SIMD (one A + one B load avg)
    dim3 grid(512), block(256);
    hipLaunchKernelGGL(lstm2_split, grid, block, 0, stream,
                       x, Wih0, Whh0, bih0, bhh0, Wih1, Whh1, bih1, bhh1, out);
}

// Round 8
// 258.773 us; speedup vs baseline: 1.5992x; 1.0993x over previous
//
#include <hip/hip_runtime.h>

#define SEQ_T   2048
#define BATCH_N 4096
#define LOG2E   1.4426950408889634f
#define K_SEG   16
#define NSEG    (SEQ_T / K_SEG)   // 128 segments

// DPP mov: quad_perm = 0x00..0xFF, ROW_MIRROR = 0x140, ROW_HALF_MIRROR = 0x141
#define DPPF(v, ctrl) __int_as_float(__builtin_amdgcn_mov_dpp(__float_as_int(v), (ctrl), 0xF, 0xF, true))
#define RHM 0x141   // quad u -> u^1 (h is quad-uniform; intra-quad scramble ok)
#define MIR 0x140   // quad u -> u^3

// Layer-split wave specialization, 128-thread blocks:
//   wave 0 = "A": layer 0 for 4 chains (16 lanes/chain, UNIT-MAJOR 4u+r)
//   wave 1 = "B": layer 1, same chains, one 16-step segment behind
// Handoff ring[32 slots][4 chains][4 units] (2 KB). A writes h0 with a
// per-segment base + immediate offsets; B reads ds_read_b128 -> all 4 h0
// components IN-LANE (natural-order input dot, no mirror DPPs on input).
// Barrier every 16 steps; segment parity gives disjoint ring halves.
// 1024 blocks x 2 waves = 2048 waves = 2 waves/SIMD.
__global__ __launch_bounds__(128, 2) void lstm2_split(
    const float* __restrict__ x,
    const float* __restrict__ Wih0, const float* __restrict__ Whh0,
    const float* __restrict__ bih0, const float* __restrict__ bhh0,
    const float* __restrict__ Wih1, const float* __restrict__ Whh1,
    const float* __restrict__ bih1, const float* __restrict__ bhh1,
    float* __restrict__ out)
{
    __shared__ float ring[32][4][4];   // [slot][chain-in-block][unit]

    const int wv    = threadIdx.x >> 6;     // 0 = A (layer0), 1 = B (layer1)
    const int lane  = threadIdx.x & 63;
    const int cpos  = lane >> 4;            // chain-in-block 0..3
    const int g16   = lane & 15;
    const int u     = g16 >> 2;             // hidden unit (quad)
    const int r     = g16 & 3;              // role 0=i 1=f 2=g 3=o
    const int row   = r * 4 + u;            // PyTorch gate-row
    const int chain = blockIdx.x * 4 + cpos;
    const bool isA  = (wv == 0);

    // Fold -log2e (sigmoid) / -2log2e (tanh row) into weights & bias.
    // A input dot: natural order (x components in-lane).
    // B input dot: natural order too (h0 arrives in-lane via ds_read_b128).
    // Recurrent dots: u-relative order (mirror DPPs).
    const float srow = (r == 2) ? (-2.0f * LOG2E) : (-LOG2E);
    float win[4], whh[4], bb;
    if (isA) {
#pragma unroll
        for (int d = 0; d < 4; ++d) {
            win[d] = Wih0[row * 4 + d]       * srow;
            whh[d] = Whh0[row * 4 + (u ^ d)] * srow;
        }
        bb = (bih0[row] + bhh0[row]) * srow;
    } else {
#pragma unroll
        for (int d = 0; d < 4; ++d) {
            win[d] = Wih1[row * 4 + d]       * srow;
            whh[d] = Whh1[row * 4 + (u ^ d)] * srow;
        }
        bb = (bih1[row] + bhh1[row]) * srow;
    }
    // g-row activation folds the cell-tanh arg scale: cs tracks -2log2e * c.
    const float csc = -2.0f * LOG2E;
    const float ka = (r == 2) ? 2.0f * csc : 1.0f;
    const float kb = (r == 2) ? -csc       : 0.0f;

    const char* __restrict__ xb = (const char*)x;
    char* __restrict__ ob = (char*)out;

    float h = 0.f, ha = 0.f, hb2 = 0.f, hc = 0.f;  // my layer's h (u-relative)
    float cs = 0.f;                                 // pre-scaled cell state

    // one cell step from pre-activation acc -> updates cs, h, mirrors
    auto cell = [&](float acc) {
        acc = fmaf(whh[0], h, fmaf(whh[1], ha,
              fmaf(whh[2], hb2, fmaf(whh[3], hc, acc))));
        float e = __builtin_amdgcn_exp2f(acc);
        float s = __builtin_amdgcn_rcpf(1.0f + e);
        float a = fmaf(ka, s, kb);
        float iv = DPPF(a, 0x00), fv = DPPF(a, 0x55);
        float gv = DPPF(a, 0xAA), ov = DPPF(a, 0xFF);
        cs = fmaf(fv, cs, iv * gv);
        float z  = __builtin_amdgcn_exp2f(cs);
        float t2 = fmaf(2.0f, __builtin_amdgcn_rcpf(1.0f + z), -1.0f);
        h  = ov * t2;
        ha = DPPF(h, RHM);
        hc = DPPF(h, MIR);
        hb2 = DPPF(ha, MIR);
    };

    if (isA) {
        // ---------------- layer-0 wave ----------------
        const unsigned xhome = (unsigned)chain * 16u;
        const unsigned XCL   = xhome + 2047u * 65536u;
        float4 xbuf[8];
        unsigned xoff = xhome;
#pragma unroll
        for (int i = 0; i < 8; ++i) {           // prologue: x(0..7)
            xbuf[i] = *(const float4*)(xb + xoff);
            xoff += 65536u;
        }
        for (int seg = 0; seg <= NSEG; ++seg) {
            __syncthreads();
            if (seg < NSEG) {
                float (*slot)[4] = ring[(seg & 1) * K_SEG];
#pragma unroll
                for (int i = 0; i < K_SEG; ++i) {
                    const float4 xv = xbuf[i & 7];
                    unsigned off = (xoff < XCL) ? xoff : XCL;   // clamp tail
                    xbuf[i & 7] = *(const float4*)(xb + off);
                    xoff += 65536u;
                    float acc = fmaf(win[0], xv.x, fmaf(win[1], xv.y,
                                fmaf(win[2], xv.z, fmaf(win[3], xv.w, bb))));
                    cell(acc);
                    if (r == 0) slot[i * 4 + cpos][u] = h;
                }
            }
        }
    } else {
        // ---------------- layer-1 wave ----------------
        unsigned ooff = (unsigned)(chain * 16 + u * 4);   // out[0][chain][u]
        for (int seg = 0; seg <= NSEG; ++seg) {
            __syncthreads();
            if (seg > 0) {
                const float (*slot)[4] = ring[((seg - 1) & 1) * K_SEG];
                float4 hr[8];
#pragma unroll
                for (int hf = 0; hf < 2; ++hf) {
#pragma unroll
                    for (int s = 0; s < 8; ++s)
                        hr[s] = *(const float4*)&slot[(hf * 8 + s) * 4 + cpos][0];
#pragma unroll
                    for (int i = 0; i < 8; ++i) {
                        const float4 X = hr[i];
                        float acc = fmaf(win[0], X.x, fmaf(win[1], X.y,
                                    fmaf(win[2], X.z, fmaf(win[3], X.w, bb))));
                        cell(acc);
                        if (r == 0) *(float*)(ob + ooff) = h;
                        ooff += 65536u;
                    }
                }
            }
        }
    }
}

extern "C" void kernel_launch(void* const* d_in, const int* in_sizes, int n_in,
                              void* d_out, int out_size, void* d_ws, size_t ws_size,
                              hipStream_t stream) {
    const float* x    = (const float*)d_in[0];
    const float* Wih0 = (const float*)d_in[1];
    const float* Whh0 = (const float*)d_in[2];
    const float* bih0 = (const float*)d_in[3];
    const float* bhh0 = (const float*)d_in[4];
    const float* Wih1 = (const float*)d_in[5];
    const float* Whh1 = (const float*)d_in[6];
    const float* bih1 = (const float*)d_in[7];
    const float* bhh1 = (const float*)d_in[8];
    float* out = (float*)d_out;

    // 1024 blocks x 2 waves (1 A + 1 B) = 2048 waves = 2 waves/SIMD
    dim3 grid(1024), block(128);
    hipLaunchKernelGGL(lstm2_split, grid, block, 0, stream,
                       x, Wih0, Whh0, bih0, bhh0, Wih1, Whh1, bih1, bhh1, out);
}

// Round 9
// 256.972 us; speedup vs baseline: 1.6104x; 1.0070x over previous
//
#include <hip/hip_runtime.h>

#define SEQ_T   2048
#define BATCH_N 4096
#define LOG2E   1.4426950408889634f
#define K_SEG   32
#define NSEG    (SEQ_T / K_SEG)   // 64 segments

// DPP mov: quad_perm = 0x00..0xFF, ROW_MIRROR = 0x140, ROW_HALF_MIRROR = 0x141
#define DPPF(v, ctrl) __int_as_float(__builtin_amdgcn_mov_dpp(__float_as_int(v), (ctrl), 0xF, 0xF, true))
#define RHM 0x141   // quad u -> u^1 (h is quad-uniform; intra-quad scramble ok)
#define MIR 0x140   // quad u -> u^3

// Layer-split wave specialization, 128-thread blocks:
//   wave 0 = "A": layer 0 for 4 chains (16 lanes/chain, UNIT-MAJOR 4u+r)
//   wave 1 = "B": layer 1, same chains, one 32-step segment behind
// Handoff ring[64 slots][4 chains][4 units] (4 KB). A writes h0 (r==0 lanes,
// 16 distinct banks); B reads ds_read_b128 -> all 4 h0 components IN-LANE
// (natural-order input dot). Barrier every 32 steps; segment parity gives
// disjoint ring halves. 1024 blocks x 2 waves = 2048 waves = 2 waves/SIMD.
__global__ __launch_bounds__(128, 2) void lstm2_split(
    const float* __restrict__ x,
    const float* __restrict__ Wih0, const float* __restrict__ Whh0,
    const float* __restrict__ bih0, const float* __restrict__ bhh0,
    const float* __restrict__ Wih1, const float* __restrict__ Whh1,
    const float* __restrict__ bih1, const float* __restrict__ bhh1,
    float* __restrict__ out)
{
    __shared__ float ring[K_SEG * 2][4][4];   // [slot][chain-in-block][unit]

    const int wv    = threadIdx.x >> 6;     // 0 = A (layer0), 1 = B (layer1)
    const int lane  = threadIdx.x & 63;
    const int cpos  = lane >> 4;            // chain-in-block 0..3
    const int g16   = lane & 15;
    const int u     = g16 >> 2;             // hidden unit (quad)
    const int r     = g16 & 3;              // role 0=i 1=f 2=g 3=o
    const int row   = r * 4 + u;            // PyTorch gate-row
    const int chain = blockIdx.x * 4 + cpos;
    const bool isA  = (wv == 0);

    // Fold -log2e (sigmoid) / -2log2e (tanh row) into weights & bias.
    // Input dots in natural order for both waves (x / LDS-h0 arrive in-lane);
    // recurrent dots in u-relative order (mirror DPPs).
    const float srow = (r == 2) ? (-2.0f * LOG2E) : (-LOG2E);
    float win[4], whh[4], bb;
    if (isA) {
#pragma unroll
        for (int d = 0; d < 4; ++d) {
            win[d] = Wih0[row * 4 + d]       * srow;
            whh[d] = Whh0[row * 4 + (u ^ d)] * srow;
        }
        bb = (bih0[row] + bhh0[row]) * srow;
    } else {
#pragma unroll
        for (int d = 0; d < 4; ++d) {
            win[d] = Wih1[row * 4 + d]       * srow;
            whh[d] = Whh1[row * 4 + (u ^ d)] * srow;
        }
        bb = (bih1[row] + bhh1[row]) * srow;
    }
    // g-row activation folds the cell-tanh arg scale: cs tracks -2log2e * c.
    const float csc = -2.0f * LOG2E;
    const float ka = (r == 2) ? 2.0f * csc : 1.0f;
    const float kb = (r == 2) ? -csc       : 0.0f;

    const char* __restrict__ xb = (const char*)x;
    char* __restrict__ ob = (char*)out;

    float h = 0.f, ha = 0.f, hb2 = 0.f, hc = 0.f;  // my layer's h (u-relative)
    float cs = 0.f;                                 // pre-scaled cell state

    // one cell step from pre-activation acc -> updates cs, h, mirrors
    auto cell = [&](float acc) {
        acc = fmaf(whh[0], h, fmaf(whh[1], ha,
              fmaf(whh[2], hb2, fmaf(whh[3], hc, acc))));
        float e = __builtin_amdgcn_exp2f(acc);
        float s = __builtin_amdgcn_rcpf(1.0f + e);
        float a = fmaf(ka, s, kb);
        float iv = DPPF(a, 0x00), fv = DPPF(a, 0x55);
        float gv = DPPF(a, 0xAA), ov = DPPF(a, 0xFF);
        cs = fmaf(fv, cs, iv * gv);
        float z  = __builtin_amdgcn_exp2f(cs);
        float t2 = fmaf(2.0f, __builtin_amdgcn_rcpf(1.0f + z), -1.0f);
        h  = ov * t2;
        ha = DPPF(h, RHM);
        hc = DPPF(h, MIR);
        hb2 = DPPF(ha, MIR);
    };

    if (isA) {
        // ---------------- layer-0 wave ----------------
        const unsigned xhome = (unsigned)chain * 16u;
        const unsigned XCL   = xhome + 2047u * 65536u;
        float4 xbuf[8];
        unsigned xoff = xhome;
#pragma unroll
        for (int i = 0; i < 8; ++i) {           // prologue: x(0..7) in flight
            xbuf[i] = *(const float4*)(xb + xoff);
            xoff += 65536u;
        }
        for (int seg = 0; seg <= NSEG; ++seg) {
            __syncthreads();
            if (seg < NSEG) {
                float* sb = &ring[(seg & 1) * K_SEG][0][0];
                const unsigned sboff = (unsigned)(cpos * 4 + u);
                if (seg < NSEG - 1) {
                    // unclamped main path (refill target always < SEQ_T)
#pragma unroll
                    for (int i = 0; i < K_SEG; ++i) {
                        const float4 xv = xbuf[i & 7];
                        xbuf[i & 7] = *(const float4*)(xb + xoff);
                        xoff += 65536u;
                        float acc = fmaf(win[0], xv.x, fmaf(win[1], xv.y,
                                    fmaf(win[2], xv.z, fmaf(win[3], xv.w, bb))));
                        cell(acc);
                        if (r == 0) sb[i * 16 + sboff] = h;
                    }
                } else {
                    // final segment: clamp refills at the sequence end
#pragma unroll
                    for (int i = 0; i < K_SEG; ++i) {
                        const float4 xv = xbuf[i & 7];
                        unsigned off = (xoff < XCL) ? xoff : XCL;
                        xbuf[i & 7] = *(const float4*)(xb + off);
                        xoff += 65536u;
                        float acc = fmaf(win[0], xv.x, fmaf(win[1], xv.y,
                                    fmaf(win[2], xv.z, fmaf(win[3], xv.w, bb))));
                        cell(acc);
                        if (r == 0) sb[i * 16 + sboff] = h;
                    }
                }
            }
        }
    } else {
        // ---------------- layer-1 wave ----------------
        unsigned ooff = (unsigned)(chain * 16 + u * 4);   // out[0][chain][u]
        for (int seg = 0; seg <= NSEG; ++seg) {
            __syncthreads();
            if (seg > 0) {
                const float* sb = &ring[((seg - 1) & 1) * K_SEG][0][0];
                const unsigned rdoff = (unsigned)(cpos * 4);
                float4 bufA[8], bufB[8];
                // quarter-pipeline: reads for q+1 issued before computing q
#pragma unroll
                for (int s = 0; s < 8; ++s)
                    bufA[s] = *(const float4*)(sb + s * 16 + rdoff);
#pragma unroll
                for (int s = 0; s < 8; ++s)
                    bufB[s] = *(const float4*)(sb + (8 + s) * 16 + rdoff);

                auto quarter = [&](float4* hr) {
#pragma unroll
                    for (int i = 0; i < 8; ++i) {
                        const float4 X = hr[i];
                        float acc = fmaf(win[0], X.x, fmaf(win[1], X.y,
                                    fmaf(win[2], X.z, fmaf(win[3], X.w, bb))));
                        cell(acc);
                        if (r == 0) *(float*)(ob + ooff) = h;
                        ooff += 65536u;
                    }
                };

                quarter(bufA);                       // q0
#pragma unroll
                for (int s = 0; s < 8; ++s)
                    bufA[s] = *(const float4*)(sb + (16 + s) * 16 + rdoff);
                quarter(bufB);                       // q1
#pragma unroll
                for (int s = 0; s < 8; ++s)
                    bufB[s] = *(const float4*)(sb + (24 + s) * 16 + rdoff);
                quarter(bufA);                       // q2
                quarter(bufB);                       // q3
            }
        }
    }
}

extern "C" void kernel_launch(void* const* d_in, const int* in_sizes, int n_in,
                              void* d_out, int out_size, void* d_ws, size_t ws_size,
                              hipStream_t stream) {
    const float* x    = (const float*)d_in[0];
    const float* Wih0 = (const float*)d_in[1];
    const float* Whh0 = (const float*)d_in[2];
    const float* bih0 = (const float*)d_in[3];
    const float* bhh0 = (const float*)d_in[4];
    const float* Wih1 = (const float*)d_in[5];
    const float* Whh1 = (const float*)d_in[6];
    const float* bih1 = (const float*)d_in[7];
    const float* bhh1 = (const float*)d_in[8];
    float* out = (float*)d_out;

    // 1024 blocks x 2 waves (1 A + 1 B) = 2048 waves = 2 waves/SIMD
    dim3 grid(1024), block(128);
    hipLaunchKernelGGL(lstm2_split, grid, block, 0, stream,
                       x, Wih0, Whh0, bih0, bhh0, Wih1, Whh1, bih1, bhh1, out);
}